// Round 1
// baseline (619.052 us; speedup 1.0000x reference)
//
#include <hip/hip_runtime.h>

#define NN 2000
#define TT 12

// workspace layout (in floats)
#define XOFF   0          // x buffer: (B,N,C,T) = 16*2000*384 = 12,288,000
#define SKOFF  12288000   // skip: (B,N,C) = 1,024,000
#define CHOFF  13312000   // ch: N*4 = 8,000
#define CMOFF  13320000   // char_m: N*4 = 8,000
#define STOFF  13328000   // stats: 3 layers * 32 (S1[16], S2[16])

__global__ void k_init(float* stats){
  int t = threadIdx.x;
  if (t < 96) stats[t] = 0.0f;
}

__global__ void k_charm(const float* __restrict__ input,
                        const float* __restrict__ charac,
                        float* __restrict__ cm)
{
  int idx = blockIdx.x*256 + threadIdx.x;
  if (idx >= NN*4) return;
  int n = idx >> 2, r = idx & 3;
  int mv = (int)input[TT];              // input[0,0,0,T]
  int m = ((mv % 12) + 12) % 12;
  int m0 = (m + 11) % 12, m2 = (m + 1) % 12;
  const float* base = charac + n*48;
  cm[idx] = (base[m0*4+r] + base[m*4+r] + base[m2*4+r]) * (1.0f/3.0f);
}

__global__ __launch_bounds__(256) void k_ch(const float* __restrict__ adj,
                                            const float* __restrict__ cm,
                                            float* __restrict__ ch)
{
  __shared__ float red[256][4];
  int n = blockIdx.x, t = threadIdx.x;
  float s0=0.f, s1=0.f, s2=0.f, s3=0.f;
  const float* arow = adj + (size_t)n*NN;
  for (int c = t; c < NN; c += 256){
    float a = arow[c];
    float4 v = *reinterpret_cast<const float4*>(cm + c*4);
    s0 = fmaf(a, v.x, s0); s1 = fmaf(a, v.y, s1);
    s2 = fmaf(a, v.z, s2); s3 = fmaf(a, v.w, s3);
  }
  red[t][0]=s0; red[t][1]=s1; red[t][2]=s2; red[t][3]=s3;
  __syncthreads();
  for (int off = 128; off > 0; off >>= 1){
    if (t < off){
      red[t][0]+=red[t+off][0]; red[t][1]+=red[t+off][1];
      red[t][2]+=red[t+off][2]; red[t][3]+=red[t+off][3];
    }
    __syncthreads();
  }
  if (t < 4) ch[n*4+t] = red[0][t];
}

__global__ __launch_bounds__(256,2) void k_layer(
    int layer,
    float* __restrict__ xbuf, float* __restrict__ skipbuf,
    const float* __restrict__ ch, float* stats,
    const float* __restrict__ input,
    const float* __restrict__ Wcw, const float* __restrict__ bcw,
    const float* __restrict__ Wcb, const float* __restrict__ bcb,
    const float* __restrict__ Wgw, const float* __restrict__ bgw,
    const float* __restrict__ Wgb, const float* __restrict__ bgb,
    const float* __restrict__ Wrw, const float* __restrict__ brw,
    const float* __restrict__ Wrb, const float* __restrict__ brb,
    const float* __restrict__ start_w, const float* __restrict__ start_b,
    const float* __restrict__ sk0w, const float* __restrict__ sk0b,
    const float* __restrict__ skw_all, const float* __restrict__ skb_all,
    const float* __restrict__ lnw_all, const float* __restrict__ lnb_all)
{
  __shared__ float wfg[9216];          // interleaved (wf,wg) pairs, idx=(o*32+c)*18+jj
  __shared__ float rwv[32*33];         // padded
  __shared__ float lnw[384], lnb[384];
  __shared__ float xs[8][388];         // padded, per-b input (post-LN / start)
  __shared__ float gsb[8][388];        // gated output
  __shared__ float xin[8][24];
  __shared__ float swv[64], sbv[32], s0wv[768], s0bv[32], skwv[384], skbv[32];
  __shared__ float fbias[32], gbias[32], rbv[32];
  __shared__ float chs[4], chb[16];
  __shared__ float muv[16], rsv[16];
  __shared__ float red1[256], red2[256];

  const int tid = threadIdx.x;
  const int n = blockIdx.x;

  for (int i = tid; i < 4;  i += 256) chs[i] = ch[n*4+i];
  for (int i = tid; i < 16; i += 256) chb[i] = ch[((i>>2)*500 + (n>>2))*4 + (i&3)];
  for (int i = tid; i < 64; i += 256) swv[i] = start_w[i];
  for (int i = tid; i < 32; i += 256){
    sbv[i] = start_b[i]; s0bv[i] = sk0b[i]; skbv[i] = skb_all[layer*32+i];
  }
  for (int i = tid; i < 768; i += 256) s0wv[i] = sk0w[i];
  for (int i = tid; i < 384; i += 256) skwv[i] = skw_all[layer*384+i];
  if (layer > 0){
    for (int i = tid; i < 384; i += 256){
      int c = i/12, t = i%12;
      size_t o = (((size_t)(layer-1)*32 + c)*NN + n)*12 + t;
      lnw[i] = lnw_all[o]; lnb[i] = lnb_all[o];
    }
    if (tid < 16){
      float S1 = stats[(layer-1)*32 + tid];
      float S2 = stats[(layer-1)*32 + 16 + tid];
      const float M = 768000.0f;
      float mu = S1 / M;
      muv[tid] = mu;
      rsv[tid] = rsqrtf(S2/M - mu*mu + 1e-5f);
    }
  }
  __syncthreads();

  const float c0 = chs[0], c1 = chs[1], c2 = chs[2], c3 = chs[3];
  for (int i = tid; i < 4608; i += 256){
    int col = layer*4608 + i;
    float wf = fmaf(c0, Wcw[col], fmaf(c1, Wcw[13824+col],
               fmaf(c2, Wcw[27648+col], fmaf(c3, Wcw[41472+col], bcw[col]))));
    float wg = fmaf(c0, Wgw[col], fmaf(c1, Wgw[13824+col],
               fmaf(c2, Wgw[27648+col], fmaf(c3, Wgw[41472+col], bgw[col]))));
    wfg[i*2]   = wf;
    wfg[i*2+1] = wg;
  }
  for (int i = tid; i < 1024; i += 256){
    int col = layer*1024 + i;
    float v = fmaf(c0, Wrw[col], fmaf(c1, Wrw[3072+col],
              fmaf(c2, Wrw[6144+col], fmaf(c3, Wrw[9216+col], brw[col]))));
    rwv[(i>>5)*33 + (i&31)] = v;
  }
  if (tid < 32){
    int oc = tid;
    int s = oc >> 3;
    int v = ((n&3)<<3) + (oc&7);               // bias reshuffle: column
    int col = layer*32 + v;
    const float* cb4 = &chb[s*4];              // bias reshuffle: source node s*500+n/4
    fbias[oc] = fmaf(cb4[0], Wcb[col], fmaf(cb4[1], Wcb[96+col],
                fmaf(cb4[2], Wcb[192+col], fmaf(cb4[3], Wcb[288+col], bcb[col]))));
    gbias[oc] = fmaf(cb4[0], Wgb[col], fmaf(cb4[1], Wgb[96+col],
                fmaf(cb4[2], Wgb[192+col], fmaf(cb4[3], Wgb[288+col], bgb[col]))));
    int colr = layer*32 + oc;
    rbv[oc] = fmaf(c0, Wrb[colr], fmaf(c1, Wrb[96+colr],
              fmaf(c2, Wrb[192+colr], fmaf(c3, Wrb[288+colr], brb[colr]))));
  }
  __syncthreads();

  for (int bo = 0; bo < 2; ++bo){
    // ---- phase A: stage per-b input (apply prev-layer LN, or start transform) ----
    if (layer == 0){
      for (int i = tid; i < 192; i += 256){
        int g = i/24, r = i%24, d = r/12, t = r%12;
        int b = bo*8+g;
        xin[g][r] = input[(((size_t)b*2 + d)*NN + n)*13 + t];
      }
      __syncthreads();
      for (int i = tid; i < 3072; i += 256){
        int g = i/384, p = i%384, c = p/12, t = p%12;
        xs[g][p] = fmaf(swv[c*2], xin[g][t], fmaf(swv[c*2+1], xin[g][12+t], sbv[c]));
      }
    } else {
      for (int i4 = tid; i4 < 768; i4 += 256){
        int g = i4/96, p4 = i4%96;
        int b = bo*8+g;
        float4 v = *reinterpret_cast<const float4*>(xbuf + ((size_t)b*NN + n)*384 + p4*4);
        int p = p4*4;
        float mu = muv[b], rs = rsv[b];
        xs[g][p]   = fmaf((v.x-mu)*rs, lnw[p],   lnb[p]);
        xs[g][p+1] = fmaf((v.y-mu)*rs, lnw[p+1], lnb[p+1]);
        xs[g][p+2] = fmaf((v.z-mu)*rs, lnw[p+2], lnb[p+2]);
        xs[g][p+3] = fmaf((v.w-mu)*rs, lnw[p+3], lnb[p+3]);
      }
    }
    __syncthreads();

    // ---- phase B: gated circular conv. thread = oc*8+g (wave-uniform slice) ----
    {
      const int oc = tid >> 3, g = tid & 7;
      const int s = oc >> 3;
      const int kk = (s==0)?2:((s==1)?3:((s==2)?6:7));
      const int lo = (s==0)?0:((s==1)?2:((s==2)?5:11));
      float fa[12], ga[12];
      const float fb = fbias[oc], gbi = gbias[oc];
      #pragma unroll
      for (int t = 0; t < 12; ++t){ fa[t] = fb; ga[t] = gbi; }
      const float* xg = xs[g];
      const float2* wrow = reinterpret_cast<const float2*>(wfg) + (oc&7)*576 + lo;
      for (int c = 0; c < 32; ++c){
        const float4* xp = reinterpret_cast<const float4*>(xg + c*12);
        float4 xA = xp[0], xB = xp[1], xC = xp[2];
        float xr[12] = {xA.x,xA.y,xA.z,xA.w, xB.x,xB.y,xB.z,xB.w, xC.x,xC.y,xC.z,xC.w};
        const float2* wp = wrow + c*18;
        #pragma unroll
        for (int j = 0; j < 7; ++j){
          if (j < kk){                       // wave-uniform branch
            float2 w = wp[j];
            #pragma unroll
            for (int t = 0; t < 12; ++t){
              int src = t + j; if (src >= 12) src -= 12;   // compile-time
              fa[t] = fmaf(xr[src], w.x, fa[t]);
              ga[t] = fmaf(xr[src], w.y, ga[t]);
            }
          }
        }
      }
      float* gg = &gsb[g][oc*12];
      #pragma unroll
      for (int t = 0; t < 12; ++t){
        float fv = 1.0f - 2.0f/(1.0f + __expf(2.0f*fa[t]));
        float gv = 1.0f/(1.0f + __expf(-ga[t]));
        gg[t] = fv * gv;
      }
    }
    __syncthreads();

    // ---- phase C/D: skip accumulate + residual matmul + stats ----
    {
      const int o = tid >> 3, g = tid & 7;
      const int b = bo*8 + g;
      float sv = 0.0f;
      const float* gc = &gsb[g][o*12];
      #pragma unroll
      for (int t = 0; t < 12; ++t) sv = fmaf(gc[t], skwv[o*12+t], sv);
      sv += skbv[o];
      size_t so = ((size_t)b*NN + n)*32 + o;
      if (layer == 0){
        float s0 = s0bv[o];
        #pragma unroll
        for (int r = 0; r < 24; ++r) s0 = fmaf(xin[g][r], s0wv[o*24+r], s0);
        skipbuf[so] = sv + s0;
      } else {
        skipbuf[so] += sv;
      }
      float acc[12];
      {
        const float rbb = rbv[o];
        const float* xg = &xs[g][o*12];
        #pragma unroll
        for (int t = 0; t < 12; ++t) acc[t] = rbb + xg[t];
      }
      for (int c = 0; c < 32; ++c){
        float rv = rwv[o*33 + c];
        const float4* gp = reinterpret_cast<const float4*>(&gsb[g][c*12]);
        float4 a = gp[0], bq = gp[1], cq = gp[2];
        acc[0]=fmaf(a.x,rv,acc[0]);  acc[1]=fmaf(a.y,rv,acc[1]);
        acc[2]=fmaf(a.z,rv,acc[2]);  acc[3]=fmaf(a.w,rv,acc[3]);
        acc[4]=fmaf(bq.x,rv,acc[4]); acc[5]=fmaf(bq.y,rv,acc[5]);
        acc[6]=fmaf(bq.z,rv,acc[6]); acc[7]=fmaf(bq.w,rv,acc[7]);
        acc[8]=fmaf(cq.x,rv,acc[8]); acc[9]=fmaf(cq.y,rv,acc[9]);
        acc[10]=fmaf(cq.z,rv,acc[10]); acc[11]=fmaf(cq.w,rv,acc[11]);
      }
      float s1 = 0.0f, s2 = 0.0f;
      float* xo = xbuf + ((size_t)b*NN + n)*384 + o*12;
      float4* xo4 = reinterpret_cast<float4*>(xo);
      xo4[0] = make_float4(acc[0],acc[1],acc[2],acc[3]);
      xo4[1] = make_float4(acc[4],acc[5],acc[6],acc[7]);
      xo4[2] = make_float4(acc[8],acc[9],acc[10],acc[11]);
      #pragma unroll
      for (int t = 0; t < 12; ++t){ s1 += acc[t]; s2 = fmaf(acc[t], acc[t], s2); }
      red1[tid] = s1; red2[tid] = s2;
    }
    __syncthreads();
    if (tid < 8){
      float s1 = 0.0f, s2 = 0.0f;
      for (int o = 0; o < 32; ++o){ s1 += red1[o*8+tid]; s2 += red2[o*8+tid]; }
      atomicAdd(&stats[layer*32 + bo*8 + tid], s1);
      atomicAdd(&stats[layer*32 + 16 + bo*8 + tid], s2);
    }
    __syncthreads();
  }
}

__global__ __launch_bounds__(256) void k_final(
    const float* __restrict__ xbuf, const float* __restrict__ skipbuf,
    const float* __restrict__ stats,
    const float* __restrict__ lnw_all, const float* __restrict__ lnb_all,
    const float* __restrict__ skEw, const float* __restrict__ skEb,
    const float* __restrict__ e1w, const float* __restrict__ e1b,
    const float* __restrict__ e2w, const float* __restrict__ e2b,
    float* __restrict__ out)
{
  __shared__ float lnw[384], lnb[384], skE[384];
  __shared__ float e1[32*33];
  __shared__ float e1bv[32], e2v[32], skEbv[32];
  __shared__ float muv[16], rsv[16];
  __shared__ float skf[8][33];
  const int tid = threadIdx.x, n = blockIdx.x;
  for (int i = tid; i < 384; i += 256){
    int c = i/12, t = i%12;
    size_t o = (((size_t)2*32 + c)*NN + n)*12 + t;
    lnw[i] = lnw_all[o]; lnb[i] = lnb_all[o];
    skE[i] = skEw[i];
  }
  for (int i = tid; i < 1024; i += 256) e1[(i>>5)*33 + (i&31)] = e1w[i];
  if (tid < 32){ e1bv[tid] = e1b[tid]; e2v[tid] = e2w[tid]; skEbv[tid] = skEb[tid]; }
  if (tid < 16){
    float S1 = stats[64+tid], S2 = stats[80+tid];
    const float M = 768000.0f;
    float mu = S1/M; muv[tid] = mu;
    rsv[tid] = rsqrtf(S2/M - mu*mu + 1e-5f);
  }
  __syncthreads();
  const float e2b0 = e2b[0];
  for (int bo = 0; bo < 2; ++bo){
    const int g = tid >> 5, c = tid & 31, b = bo*8 + g;
    const float4* xp = reinterpret_cast<const float4*>(xbuf + ((size_t)b*NN+n)*384 + c*12);
    float4 xA = xp[0], xB = xp[1], xC = xp[2];
    float xr[12] = {xA.x,xA.y,xA.z,xA.w, xB.x,xB.y,xB.z,xB.w, xC.x,xC.y,xC.z,xC.w};
    const float mu = muv[b], rs = rsv[b];
    float se = 0.0f;
    #pragma unroll
    for (int t = 0; t < 12; ++t){
      float xv = fmaf((xr[t]-mu)*rs, lnw[c*12+t], lnb[c*12+t]);
      se = fmaf(xv, skE[c*12+t], se);
    }
    float sk = se + skEbv[c] + skipbuf[((size_t)b*NN+n)*32 + c];
    skf[g][c] = fmaxf(sk, 0.0f);
    __syncthreads();
    float acc = e1bv[c];
    #pragma unroll
    for (int cc = 0; cc < 32; ++cc) acc = fmaf(skf[g][cc], e1[c*33+cc], acc);
    float y1 = fmaxf(acc, 0.0f);
    float part = y1 * e2v[c];
    #pragma unroll
    for (int off = 16; off > 0; off >>= 1) part += __shfl_down(part, off, 32);
    if (c == 0) out[(size_t)b*NN + n] = part + e2b0;
    __syncthreads();
  }
}

extern "C" void kernel_launch(void* const* d_in, const int* in_sizes, int n_in,
                              void* d_out, int out_size, void* d_ws, size_t ws_size,
                              hipStream_t stream)
{
  (void)in_sizes; (void)n_in; (void)out_size; (void)ws_size;
  const float* input   = (const float*)d_in[0];
  const float* adj     = (const float*)d_in[1];
  const float* charac  = (const float*)d_in[2];
  const float* Wcw     = (const float*)d_in[3];
  const float* bcw     = (const float*)d_in[4];
  const float* Wcb     = (const float*)d_in[5];
  const float* bcb     = (const float*)d_in[6];
  const float* Wgw     = (const float*)d_in[7];
  const float* bgw     = (const float*)d_in[8];
  const float* Wgb     = (const float*)d_in[9];
  const float* bgb     = (const float*)d_in[10];
  const float* Wrw     = (const float*)d_in[11];
  const float* brw     = (const float*)d_in[12];
  const float* Wrb     = (const float*)d_in[13];
  const float* brb     = (const float*)d_in[14];
  const float* start_w = (const float*)d_in[15];
  const float* start_b = (const float*)d_in[16];
  const float* sk0w    = (const float*)d_in[17];
  const float* sk0b    = (const float*)d_in[18];
  const float* skw     = (const float*)d_in[19];
  const float* skb     = (const float*)d_in[20];
  const float* skEw    = (const float*)d_in[21];
  const float* skEb    = (const float*)d_in[22];
  const float* lnw     = (const float*)d_in[23];
  const float* lnb     = (const float*)d_in[24];
  const float* e1w     = (const float*)d_in[25];
  const float* e1b     = (const float*)d_in[26];
  const float* e2w     = (const float*)d_in[27];
  const float* e2b     = (const float*)d_in[28];

  float* ws     = (float*)d_ws;
  float* xbuf   = ws + XOFF;
  float* skipb  = ws + SKOFF;
  float* chbuf  = ws + CHOFF;
  float* cmbuf  = ws + CMOFF;
  float* stats  = ws + STOFF;
  float* outp   = (float*)d_out;

  k_init<<<1, 128, 0, stream>>>(stats);
  k_charm<<<32, 256, 0, stream>>>(input, charac, cmbuf);
  k_ch<<<NN, 256, 0, stream>>>(adj, cmbuf, chbuf);
  for (int layer = 0; layer < 3; ++layer){
    k_layer<<<NN, 256, 0, stream>>>(layer, xbuf, skipb, chbuf, stats, input,
        Wcw, bcw, Wcb, bcb, Wgw, bgw, Wgb, bgb, Wrw, brw, Wrb, brb,
        start_w, start_b, sk0w, sk0b, skw, skb, lnw, lnb);
  }
  k_final<<<NN, 256, 0, stream>>>(xbuf, skipb, stats, lnw, lnb,
      skEw, skEb, e1w, e1b, e2w, e2b, outp);
}

// Round 2
// 432.012 us; speedup vs baseline: 1.4329x; 1.4329x over previous
//
#include <hip/hip_runtime.h>

#define NN 2000
#define TT 12

// workspace layout (in floats)
#define XOFF   0          // x buffer: (B,N,C,T) = 16*2000*384 = 12,288,000
#define SKOFF  12288000   // skip: (B,N,C) = 1,024,000
#define CHOFF  13312000   // ch: N*4 = 8,000
#define CMOFF  13320000   // char_m: N*4 = 8,000
#define STOFF  13328000   // stats: 3 layers * 32 (S1[16], S2[16])

__device__ __forceinline__ unsigned int f2bf(float x){
  unsigned int u = __float_as_uint(x);
  return (u + 0x7fffu + ((u >> 16) & 1u)) >> 16;
}
__device__ __forceinline__ unsigned int pk2(float a, float b){
  return f2bf(a) | (f2bf(b) << 16);
}
__device__ __forceinline__ float bflo(unsigned int u){ return __uint_as_float(u << 16); }
__device__ __forceinline__ float bfhi(unsigned int u){ return __uint_as_float(u & 0xffff0000u); }
__device__ __forceinline__ float fsig(float x){ return 1.0f/(1.0f + __expf(-x)); }
__device__ __forceinline__ float ftanh(float x){ return 1.0f - 2.0f/(1.0f + __expf(2.0f*x)); }

__global__ void k_init(float* stats){
  int t = threadIdx.x;
  if (t < 96) stats[t] = 0.0f;
}

__global__ void k_charm(const float* __restrict__ input,
                        const float* __restrict__ charac,
                        float* __restrict__ cm)
{
  int idx = blockIdx.x*256 + threadIdx.x;
  if (idx >= NN*4) return;
  int n = idx >> 2, r = idx & 3;
  int mv = (int)input[TT];              // input[0,0,0,T]
  int m = ((mv % 12) + 12) % 12;
  int m0 = (m + 11) % 12, m2 = (m + 1) % 12;
  const float* base = charac + n*48;
  cm[idx] = (base[m0*4+r] + base[m*4+r] + base[m2*4+r]) * (1.0f/3.0f);
}

__global__ __launch_bounds__(256) void k_ch(const float* __restrict__ adj,
                                            const float* __restrict__ cm,
                                            float* __restrict__ ch)
{
  __shared__ float red[256][4];
  int n = blockIdx.x, t = threadIdx.x;
  float s0=0.f, s1=0.f, s2=0.f, s3=0.f;
  const float* arow = adj + (size_t)n*NN;
  for (int c = t; c < NN; c += 256){
    float a = arow[c];
    float4 v = *reinterpret_cast<const float4*>(cm + c*4);
    s0 = fmaf(a, v.x, s0); s1 = fmaf(a, v.y, s1);
    s2 = fmaf(a, v.z, s2); s3 = fmaf(a, v.w, s3);
  }
  red[t][0]=s0; red[t][1]=s1; red[t][2]=s2; red[t][3]=s3;
  __syncthreads();
  for (int off = 128; off > 0; off >>= 1){
    if (t < off){
      red[t][0]+=red[t+off][0]; red[t][1]+=red[t+off][1];
      red[t][2]+=red[t+off][2]; red[t][3]+=red[t+off][3];
    }
    __syncthreads();
  }
  if (t < 4) ch[n*4+t] = red[0][t];
}

// conv for a complementary slice pair: A has KKA taps at LOA, B has KKB at LOB.
// Both output channels share the same weight row o (= oc&7) and the same x.
template<int LOA,int KKA,int LOB,int KKB>
__device__ __forceinline__ void conv_pair(
    const float* __restrict__ xg, const unsigned int* __restrict__ wrow,
    float fbA, float gbA, float fbB, float gbB,
    float* __restrict__ gA, float* __restrict__ gB)
{
  float faA[12], gaA[12], faB[12], gaB[12];
#pragma unroll
  for (int t=0;t<12;++t){ faA[t]=fbA; gaA[t]=gbA; faB[t]=fbB; gaB[t]=gbB; }
  for (int c=0;c<32;++c){
    const float4* xp = reinterpret_cast<const float4*>(xg + c*12);
    float4 x0=xp[0], x1=xp[1], x2=xp[2];
    float xr[12]={x0.x,x0.y,x0.z,x0.w, x1.x,x1.y,x1.z,x1.w, x2.x,x2.y,x2.z,x2.w};
    const unsigned int* wp = wrow + c*18;
#pragma unroll
    for (int j=0;j<KKA;++j){
      unsigned int w = wp[LOA+j];
      float wx=bflo(w), wy=bfhi(w);
#pragma unroll
      for (int t=0;t<12;++t){ int s=t+j; if (s>=12) s-=12;
        faA[t]=fmaf(xr[s],wx,faA[t]); gaA[t]=fmaf(xr[s],wy,gaA[t]); }
    }
#pragma unroll
    for (int j=0;j<KKB;++j){
      unsigned int w = wp[LOB+j];
      float wx=bflo(w), wy=bfhi(w);
#pragma unroll
      for (int t=0;t<12;++t){ int s=t+j; if (s>=12) s-=12;
        faB[t]=fmaf(xr[s],wx,faB[t]); gaB[t]=fmaf(xr[s],wy,gaB[t]); }
    }
  }
#pragma unroll
  for (int t=0;t<12;++t){
    gA[t]=ftanh(faA[t])*fsig(gaA[t]);
    gB[t]=ftanh(faB[t])*fsig(gaB[t]);
  }
}

__global__ __launch_bounds__(256,2) void k_layer(
    int layer,
    float* __restrict__ xbuf, float* __restrict__ skipbuf,
    const float* __restrict__ ch, float* stats,
    const float* __restrict__ input,
    const float* __restrict__ Wcw, const float* __restrict__ bcw,
    const float* __restrict__ Wcb, const float* __restrict__ bcb,
    const float* __restrict__ Wgw, const float* __restrict__ bgw,
    const float* __restrict__ Wgb, const float* __restrict__ bgb,
    const float* __restrict__ Wrw, const float* __restrict__ brw,
    const float* __restrict__ Wrb, const float* __restrict__ brb,
    const float* __restrict__ start_w, const float* __restrict__ start_b,
    const float* __restrict__ sk0w, const float* __restrict__ sk0b,
    const float* __restrict__ skw_all, const float* __restrict__ skb_all,
    const float* __restrict__ lnw_all, const float* __restrict__ lnb_all)
{
  __shared__ unsigned int wfgh[4640];   // 8 rows (o) x 580 u32 (stride%32==4, conflict-free)
  __shared__ float rwv[1056];           // 32 x 33 padded
  __shared__ float lnw[384], lnb[384];
  __shared__ float xs[16][388];         // all 16 batches, fp32, stride%32==4
  __shared__ unsigned int gsbh[16][196];// gated out, packed bf16 pairs along t
  __shared__ float xin[16][24];
  __shared__ float swv[64], sbv[32], s0wv[768], s0bv[32], skwv[384], skbv[32];
  __shared__ float fbias[32], gbias[32], rbv[32];
  __shared__ float chs[4], chb[16];
  __shared__ float muv[16], rsv[16];
  __shared__ float red1[256], red2[256];

  const int tid = threadIdx.x;
  const int n = blockIdx.x;

  for (int i = tid; i < 4;  i += 256) chs[i] = ch[n*4+i];
  for (int i = tid; i < 16; i += 256) chb[i] = ch[((i>>2)*500 + (n>>2))*4 + (i&3)];
  for (int i = tid; i < 64; i += 256) swv[i] = start_w[i];
  for (int i = tid; i < 32; i += 256){
    sbv[i] = start_b[i]; s0bv[i] = sk0b[i]; skbv[i] = skb_all[layer*32+i];
  }
  for (int i = tid; i < 768; i += 256) s0wv[i] = sk0w[i];
  for (int i = tid; i < 384; i += 256) skwv[i] = skw_all[layer*384+i];
  if (layer == 0){
    for (int i = tid; i < 384; i += 256){
      int g = i/24, r = i%24, d = r/12, t = r%12;
      xin[g][r] = input[(((size_t)g*2 + d)*NN + n)*13 + t];
    }
  } else {
    for (int i = tid; i < 384; i += 256){
      int c = i/12, t = i%12;
      size_t o = (((size_t)(layer-1)*32 + c)*NN + n)*12 + t;
      lnw[i] = lnw_all[o]; lnb[i] = lnb_all[o];
    }
    if (tid < 16){
      float S1 = stats[(layer-1)*32 + tid];
      float S2 = stats[(layer-1)*32 + 16 + tid];
      const float M = 768000.0f;
      float mu = S1 / M;
      muv[tid] = mu;
      rsv[tid] = rsqrtf(S2/M - mu*mu + 1e-5f);
    }
  }

  const float c0 = chs[0], c1 = chs[1], c2 = chs[2], c3 = chs[3];
  // NOTE: chs written by tid 0..3 this same pass; but every thread re-reads via
  // __syncthreads-protected path below for weight gen. To be safe, sync first.
  __syncthreads();
  {
    const float d0 = chs[0], d1 = chs[1], d2 = chs[2], d3 = chs[3];
    for (int i = tid; i < 4608; i += 256){
      int col = layer*4608 + i;
      float wf = fmaf(d0, Wcw[col], fmaf(d1, Wcw[13824+col],
                 fmaf(d2, Wcw[27648+col], fmaf(d3, Wcw[41472+col], bcw[col]))));
      float wg = fmaf(d0, Wgw[col], fmaf(d1, Wgw[13824+col],
                 fmaf(d2, Wgw[27648+col], fmaf(d3, Wgw[41472+col], bgw[col]))));
      int row = i/576, rest = i%576;        // i = o*576 + c*18 + jj
      wfgh[row*580 + rest] = pk2(wf, wg);
    }
    for (int i = tid; i < 1024; i += 256){
      int col = layer*1024 + i;
      float v = fmaf(d0, Wrw[col], fmaf(d1, Wrw[3072+col],
                fmaf(d2, Wrw[6144+col], fmaf(d3, Wrw[9216+col], brw[col]))));
      rwv[(i>>5)*33 + (i&31)] = v;
    }
    if (tid < 32){
      int oc = tid;
      int s = oc >> 3;
      int v = ((n&3)<<3) + (oc&7);               // bias reshuffle: column
      int col = layer*32 + v;
      const float* cb4 = &chb[s*4];              // bias reshuffle: node s*500+n/4
      fbias[oc] = fmaf(cb4[0], Wcb[col], fmaf(cb4[1], Wcb[96+col],
                  fmaf(cb4[2], Wcb[192+col], fmaf(cb4[3], Wcb[288+col], bcb[col]))));
      gbias[oc] = fmaf(cb4[0], Wgb[col], fmaf(cb4[1], Wgb[96+col],
                  fmaf(cb4[2], Wgb[192+col], fmaf(cb4[3], Wgb[288+col], gbias[0]*0.0f + bgb[col]))));
      int colr = layer*32 + oc;
      rbv[oc] = fmaf(c0, Wrb[colr], fmaf(c1, Wrb[96+colr],
                fmaf(c2, Wrb[192+colr], fmaf(c3, Wrb[288+colr], brb[colr]))));
    }
  }
  __syncthreads();

  // ---- phase A: stage xs for all 16 batches (LN of prev x, or start transform) ----
  if (layer == 0){
    for (int i = tid; i < 6144; i += 256){
      int bq = i/384, pq = i%384, c = pq/12, t = pq%12;
      xs[bq][pq] = fmaf(swv[c*2], xin[bq][t], fmaf(swv[c*2+1], xin[bq][12+t], sbv[c]));
    }
  } else {
    for (int i4 = tid; i4 < 1536; i4 += 256){
      int bq = i4/96, p4 = i4%96;
      float4 v = *reinterpret_cast<const float4*>(xbuf + ((size_t)bq*NN + n)*384 + p4*4);
      int pq = p4*4;
      float mu = muv[bq], rs = rsv[bq];
      xs[bq][pq]   = fmaf((v.x-mu)*rs, lnw[pq],   lnb[pq]);
      xs[bq][pq+1] = fmaf((v.y-mu)*rs, lnw[pq+1], lnb[pq+1]);
      xs[bq][pq+2] = fmaf((v.z-mu)*rs, lnw[pq+2], lnb[pq+2]);
      xs[bq][pq+3] = fmaf((v.w-mu)*rs, lnw[pq+3], lnb[pq+3]);
    }
  }
  __syncthreads();

  // ---- phase B: gated conv, balanced pairs. thread = p*16 + b ----
  // p<8 : oc_a=p    (k=2, lo=0),  oc_b=24+p (k=7, lo=11), weight row o=p
  // p>=8: oc_a=p    (k=3, lo=2),  oc_b=8+p  (k=6, lo=5),  weight row o=p-8
  {
    const int p = tid >> 4, b = tid & 15;
    float gA[12], gB[12];
    int oc_a, oc_b;
    if (p < 8){
      oc_a = p; oc_b = 24 + p;
      conv_pair<0,2,11,7>(xs[b], wfgh + p*580,
        fbias[oc_a], gbias[oc_a], fbias[oc_b], gbias[oc_b], gA, gB);
    } else {
      oc_a = p; oc_b = 8 + p;
      conv_pair<2,3,5,6>(xs[b], wfgh + (p-8)*580,
        fbias[oc_a], gbias[oc_a], fbias[oc_b], gbias[oc_b], gA, gB);
    }
    // skip accumulation in fp32 straight from registers
    float skA = skbv[oc_a], skB = skbv[oc_b];
#pragma unroll
    for (int t=0;t<12;++t){
      skA = fmaf(gA[t], skwv[oc_a*12+t], skA);
      skB = fmaf(gB[t], skwv[oc_b*12+t], skB);
    }
    size_t so = ((size_t)b*NN + n)*32;
    if (layer == 0){
      float s0A = s0bv[oc_a], s0B = s0bv[oc_b];
#pragma unroll
      for (int r=0;r<24;++r){
        float xv = xin[b][r];
        s0A = fmaf(xv, s0wv[oc_a*24+r], s0A);
        s0B = fmaf(xv, s0wv[oc_b*24+r], s0B);
      }
      skipbuf[so+oc_a] = skA + s0A;
      skipbuf[so+oc_b] = skB + s0B;
    } else {
      skipbuf[so+oc_a] += skA;
      skipbuf[so+oc_b] += skB;
    }
    // pack gated outputs to LDS (bf16 pairs along t)
    uint2* pa = reinterpret_cast<uint2*>(&gsbh[b][oc_a*6]);
    uint2* pb = reinterpret_cast<uint2*>(&gsbh[b][oc_b*6]);
#pragma unroll
    for (int i=0;i<3;++i){
      pa[i] = make_uint2(pk2(gA[4*i],gA[4*i+1]), pk2(gA[4*i+2],gA[4*i+3]));
      pb[i] = make_uint2(pk2(gB[4*i],gB[4*i+1]), pk2(gB[4*i+2],gB[4*i+3]));
    }
  }
  __syncthreads();

  // ---- phase C: residual matmul + stats ----
  {
    const int p = tid >> 4, b = tid & 15;
    const int oc_a = p, oc_b = (p < 8) ? 24 + p : 8 + p;
    float accA[12], accB[12];
    {
      const float rbA = rbv[oc_a], rbB = rbv[oc_b];
      const float4* xa = reinterpret_cast<const float4*>(&xs[b][oc_a*12]);
      const float4* xb = reinterpret_cast<const float4*>(&xs[b][oc_b*12]);
#pragma unroll
      for (int q=0;q<3;++q){
        float4 va = xa[q], vb = xb[q];
        accA[4*q]=rbA+va.x; accA[4*q+1]=rbA+va.y; accA[4*q+2]=rbA+va.z; accA[4*q+3]=rbA+va.w;
        accB[4*q]=rbB+vb.x; accB[4*q+1]=rbB+vb.y; accB[4*q+2]=rbB+vb.z; accB[4*q+3]=rbB+vb.w;
      }
    }
    for (int c = 0; c < 32; ++c){
      float rA = rwv[oc_a*33 + c], rB = rwv[oc_b*33 + c];
      const uint2* gp = reinterpret_cast<const uint2*>(&gsbh[b][c*6]);
      uint2 u0 = gp[0], u1 = gp[1], u2 = gp[2];
      float gg[12];
      gg[0]=bflo(u0.x); gg[1]=bfhi(u0.x); gg[2]=bflo(u0.y); gg[3]=bfhi(u0.y);
      gg[4]=bflo(u1.x); gg[5]=bfhi(u1.x); gg[6]=bflo(u1.y); gg[7]=bfhi(u1.y);
      gg[8]=bflo(u2.x); gg[9]=bfhi(u2.x); gg[10]=bflo(u2.y); gg[11]=bfhi(u2.y);
#pragma unroll
      for (int t=0;t<12;++t){
        accA[t] = fmaf(gg[t], rA, accA[t]);
        accB[t] = fmaf(gg[t], rB, accB[t]);
      }
    }
    float* xoA = xbuf + ((size_t)b*NN + n)*384 + oc_a*12;
    float* xoB = xbuf + ((size_t)b*NN + n)*384 + oc_b*12;
    float4* a4 = reinterpret_cast<float4*>(xoA);
    float4* b4 = reinterpret_cast<float4*>(xoB);
    a4[0]=make_float4(accA[0],accA[1],accA[2],accA[3]);
    a4[1]=make_float4(accA[4],accA[5],accA[6],accA[7]);
    a4[2]=make_float4(accA[8],accA[9],accA[10],accA[11]);
    b4[0]=make_float4(accB[0],accB[1],accB[2],accB[3]);
    b4[1]=make_float4(accB[4],accB[5],accB[6],accB[7]);
    b4[2]=make_float4(accB[8],accB[9],accB[10],accB[11]);
    float s1 = 0.0f, s2 = 0.0f;
#pragma unroll
    for (int t=0;t<12;++t){
      s1 += accA[t] + accB[t];
      s2 = fmaf(accA[t], accA[t], fmaf(accB[t], accB[t], s2));
    }
    red1[tid] = s1; red2[tid] = s2;
  }
  __syncthreads();
  if (tid < 16){
    float s1 = 0.0f, s2 = 0.0f;
    for (int p2 = 0; p2 < 16; ++p2){ s1 += red1[p2*16 + tid]; s2 += red2[p2*16 + tid]; }
    atomicAdd(&stats[layer*32 + tid], s1);
    atomicAdd(&stats[layer*32 + 16 + tid], s2);
  }
}

__global__ __launch_bounds__(256) void k_final(
    const float* __restrict__ xbuf, const float* __restrict__ skipbuf,
    const float* __restrict__ stats,
    const float* __restrict__ lnw_all, const float* __restrict__ lnb_all,
    const float* __restrict__ skEw, const float* __restrict__ skEb,
    const float* __restrict__ e1w, const float* __restrict__ e1b,
    const float* __restrict__ e2w, const float* __restrict__ e2b,
    float* __restrict__ out)
{
  __shared__ float lnw[384], lnb[384], skE[384];
  __shared__ float e1[32*33];
  __shared__ float e1bv[32], e2v[32], skEbv[32];
  __shared__ float muv[16], rsv[16];
  __shared__ float skf[8][33];
  const int tid = threadIdx.x, n = blockIdx.x;
  for (int i = tid; i < 384; i += 256){
    int c = i/12, t = i%12;
    size_t o = (((size_t)2*32 + c)*NN + n)*12 + t;
    lnw[i] = lnw_all[o]; lnb[i] = lnb_all[o];
    skE[i] = skEw[i];
  }
  for (int i = tid; i < 1024; i += 256) e1[(i>>5)*33 + (i&31)] = e1w[i];
  if (tid < 32){ e1bv[tid] = e1b[tid]; e2v[tid] = e2w[tid]; skEbv[tid] = skEb[tid]; }
  if (tid < 16){
    float S1 = stats[64+tid], S2 = stats[80+tid];
    const float M = 768000.0f;
    float mu = S1/M; muv[tid] = mu;
    rsv[tid] = rsqrtf(S2/M - mu*mu + 1e-5f);
  }
  __syncthreads();
  const float e2b0 = e2b[0];
  for (int bo = 0; bo < 2; ++bo){
    const int g = tid >> 5, c = tid & 31, b = bo*8 + g;
    const float4* xp = reinterpret_cast<const float4*>(xbuf + ((size_t)b*NN+n)*384 + c*12);
    float4 xA = xp[0], xB = xp[1], xC = xp[2];
    float xr[12] = {xA.x,xA.y,xA.z,xA.w, xB.x,xB.y,xB.z,xB.w, xC.x,xC.y,xC.z,xC.w};
    const float mu = muv[b], rs = rsv[b];
    float se = 0.0f;
#pragma unroll
    for (int t = 0; t < 12; ++t){
      float xv = fmaf((xr[t]-mu)*rs, lnw[c*12+t], lnb[c*12+t]);
      se = fmaf(xv, skE[c*12+t], se);
    }
    float sk = se + skEbv[c] + skipbuf[((size_t)b*NN+n)*32 + c];
    skf[g][c] = fmaxf(sk, 0.0f);
    __syncthreads();
    float acc = e1bv[c];
#pragma unroll
    for (int cc = 0; cc < 32; ++cc) acc = fmaf(skf[g][cc], e1[c*33+cc], acc);
    float y1 = fmaxf(acc, 0.0f);
    float part = y1 * e2v[c];
#pragma unroll
    for (int off = 16; off > 0; off >>= 1) part += __shfl_down(part, off, 32);
    if (c == 0) out[(size_t)b*NN + n] = part + e2b0;
    __syncthreads();
  }
}

extern "C" void kernel_launch(void* const* d_in, const int* in_sizes, int n_in,
                              void* d_out, int out_size, void* d_ws, size_t ws_size,
                              hipStream_t stream)
{
  (void)in_sizes; (void)n_in; (void)out_size; (void)ws_size;
  const float* input   = (const float*)d_in[0];
  const float* adj     = (const float*)d_in[1];
  const float* charac  = (const float*)d_in[2];
  const float* Wcw     = (const float*)d_in[3];
  const float* bcw     = (const float*)d_in[4];
  const float* Wcb     = (const float*)d_in[5];
  const float* bcb     = (const float*)d_in[6];
  const float* Wgw     = (const float*)d_in[7];
  const float* bgw     = (const float*)d_in[8];
  const float* Wgb     = (const float*)d_in[9];
  const float* bgb     = (const float*)d_in[10];
  const float* Wrw     = (const float*)d_in[11];
  const float* brw     = (const float*)d_in[12];
  const float* Wrb     = (const float*)d_in[13];
  const float* brb     = (const float*)d_in[14];
  const float* start_w = (const float*)d_in[15];
  const float* start_b = (const float*)d_in[16];
  const float* sk0w    = (const float*)d_in[17];
  const float* sk0b    = (const float*)d_in[18];
  const float* skw     = (const float*)d_in[19];
  const float* skb     = (const float*)d_in[20];
  const float* skEw    = (const float*)d_in[21];
  const float* skEb    = (const float*)d_in[22];
  const float* lnw     = (const float*)d_in[23];
  const float* lnb     = (const float*)d_in[24];
  const float* e1w     = (const float*)d_in[25];
  const float* e1b     = (const float*)d_in[26];
  const float* e2w     = (const float*)d_in[27];
  const float* e2b     = (const float*)d_in[28];

  float* ws     = (float*)d_ws;
  float* xbuf   = ws + XOFF;
  float* skipb  = ws + SKOFF;
  float* chbuf  = ws + CHOFF;
  float* cmbuf  = ws + CMOFF;
  float* stats  = ws + STOFF;
  float* outp   = (float*)d_out;

  k_init<<<1, 128, 0, stream>>>(stats);
  k_charm<<<32, 256, 0, stream>>>(input, charac, cmbuf);
  k_ch<<<NN, 256, 0, stream>>>(adj, cmbuf, chbuf);
  for (int layer = 0; layer < 3; ++layer){
    k_layer<<<NN, 256, 0, stream>>>(layer, xbuf, skipb, chbuf, stats, input,
        Wcw, bcw, Wcb, bcb, Wgw, bgw, Wgb, bgb, Wrw, brw, Wrb, brb,
        start_w, start_b, sk0w, sk0b, skw, skb, lnw, lnb);
  }
  k_final<<<NN, 256, 0, stream>>>(xbuf, skipb, stats, lnw, lnb,
      skEw, skEb, e1w, e1b, e2w, e2b, outp);
}